// Round 1
// baseline (532.072 us; speedup 1.0000x reference)
//
#include <hip/hip_runtime.h>
#include <hip/hip_bf16.h>
#include <stdint.h>

typedef short   s16x8  __attribute__((ext_vector_type(8)));
typedef float   f32x4a __attribute__((ext_vector_type(4)));
typedef unsigned short u16x4 __attribute__((ext_vector_type(4)));
typedef int     i32x4  __attribute__((ext_vector_type(4)));

#define D_IN   4096
#define D_OUT  4096
#define RANK   16
#define KEXT   4128   // 4096 + 16 (lora) + 16 (zero pad); 129 * 32
#define MROWS  8192   // 4 * 2048

__device__ __forceinline__ uint16_t f32_to_bf16(float f) {
  union { float f; uint32_t u; } v; v.f = f;
  uint32_t u = v.u;
  return (uint16_t)((u + 0x7FFFu + ((u >> 16) & 1u)) >> 16);  // RNE
}

__device__ __forceinline__ void gload16(void* lds, const void* g) {
  __builtin_amdgcn_global_load_lds(
      (const __attribute__((address_space(1))) uint32_t*)g,
      (__attribute__((address_space(3))) uint32_t*)lds, 16, 0, 0);
}

// ---- 1) x fp32 -> bf16 into x_ext (row stride KEXT) --------------------
extern "C" __global__ void k_conv_x(const float* __restrict__ x,
                                    uint16_t* __restrict__ xext) {
  int64_t idx = (int64_t)blockIdx.x * blockDim.x + threadIdx.x;  // float4 index
  const int64_t total  = (int64_t)MROWS * (D_IN / 4);
  const int64_t stride = (int64_t)gridDim.x * blockDim.x;
  for (; idx < total; idx += stride) {
    int64_t m = idx >> 10;              // D_IN/4 = 1024
    int k4 = (int)(idx & 1023);
    f32x4a v = *(const f32x4a*)(x + m * D_IN + (int64_t)k4 * 4);
    u16x4 o;
#pragma unroll
    for (int j = 0; j < 4; j++) o[j] = f32_to_bf16(v[j]);
    *(u16x4*)(xext + m * KEXT + k4 * 4) = o;
  }
}

// ---- 2) xA = x_bf16 @ loraA^T via MFMA, into x_ext cols [4096,4128) ----
// block = 256 threads = 4 waves; each wave computes 16 rows x 16 r's.
extern "C" __global__ __launch_bounds__(256) void k_xa(
    const uint16_t* __restrict__ xext_ro, uint16_t* __restrict__ xext_rw,
    const float* __restrict__ loraA) {
  const int tid = threadIdx.x, w = tid >> 6, l = tid & 63;
  const int l15 = l & 15, lk = l >> 4;
  const int64_t row0 = (int64_t)blockIdx.x * 64 + w * 16;
  f32x4a acc = {0.f, 0.f, 0.f, 0.f};
  const uint16_t* xrow = xext_ro + (row0 + l15) * KEXT + lk * 8;
  const float*    arow = loraA + (int64_t)l15 * D_IN + lk * 8;
  for (int k0 = 0; k0 < D_IN; k0 += 32) {
    s16x8 af = *(const s16x8*)(xrow + k0);
    s16x8 bf;
#pragma unroll
    for (int j = 0; j < 8; j++) bf[j] = (short)f32_to_bf16(arow[k0 + j]);
    acc = __builtin_amdgcn_mfma_f32_16x16x32_bf16(af, bf, acc, 0, 0, 0);
  }
  // C/D layout: col = l&15 (= r), row = (l>>4)*4 + reg
#pragma unroll
  for (int reg = 0; reg < 4; reg++) {
    int64_t m = row0 + lk * 4 + reg;
    xext_rw[m * KEXT + D_IN + l15]        = f32_to_bf16(acc[reg]);
    xext_rw[m * KEXT + D_IN + RANK + l15] = (uint16_t)0;  // zero pad
  }
}

// ---- 3) qweight int -> bf16 + LoRA-B tail into w_ext -------------------
extern "C" __global__ void k_conv_w(const int* __restrict__ qw,
                                    const int* __restrict__ qscale,
                                    const float* __restrict__ meta,
                                    const float* __restrict__ loraB,
                                    uint16_t* __restrict__ wext) {
  const int n = blockIdx.x, t = threadIdx.x;
  const int* row  = qw   + (int64_t)n * D_IN;
  uint16_t*  orow = wext + (int64_t)n * KEXT;
  const int base = t * 16;
#pragma unroll
  for (int j = 0; j < 4; j++) {
    i32x4 v = *(const i32x4*)(row + base + j * 4);
    u16x4 o;
#pragma unroll
    for (int e = 0; e < 4; e++) o[e] = f32_to_bf16((float)v[e]);  // exact
    *(u16x4*)(orow + base + j * 4) = o;
  }
  if (t < RANK) {
    float sr = (float)qscale[n] * meta[0];
    orow[D_IN + t] = f32_to_bf16(2.0f * loraB[n * RANK + t] / sr);
  } else if (t < 2 * RANK) {
    orow[D_IN + t] = (uint16_t)0;  // zero pad
  }
}

// ---- 4) main GEMM: C = Xext @ Wext^T, epilogue *scale_row + bias -------
// 128x128 tile, BK=32, 4 waves of 64x64 (4x4 frags of 16x16x32 bf16 MFMA).
// global_load_lds(16B) direct staging, both-sides XOR swizzle:
//   granule slot = chunk ^ ((row>>1)&3)  -> 2-way (free) bank pattern.
extern "C" __global__ __launch_bounds__(256, 2) void k_gemm(
    const uint16_t* __restrict__ A, const uint16_t* __restrict__ B,
    const int* __restrict__ qscale, const float* __restrict__ meta,
    const float* __restrict__ bias, float* __restrict__ out) {
  __shared__ uint16_t ldsA[128 * 32];   // 8 KB
  __shared__ uint16_t ldsB[128 * 32];   // 8 KB
  const int tid = threadIdx.x;
  // XCD-aware swizzle over 2048 blocks (2048 % 8 == 0 -> bijective)
  const int bid = blockIdx.x;
  const int swz = (bid & 7) * 256 + (bid >> 3);
  const int mtile = swz >> 5;   // 64 m-tiles
  const int ntile = swz & 31;   // 32 n-tiles

  const int w = tid >> 6, l = tid & 63;
  const int wm = w >> 1, wn = w & 1;
  const int l15 = l & 15, lk = l >> 4;

  const uint16_t* Ap = A + (int64_t)mtile * 128 * KEXT;
  const uint16_t* Bp = B + (int64_t)ntile * 128 * KEXT;

  // staging: per call c, granule g = c*256+tid; row r=g>>2, slot=g&3,
  // source chunk = slot ^ ((r>>1)&3); LDS dest linear (wave-uniform+lane*16).
  int64_t src_off[2];
  int lds_off[2];
#pragma unroll
  for (int c = 0; c < 2; c++) {
    int g = c * 256 + tid;
    int r = g >> 2, sl = g & 3;
    int cc = sl ^ ((r >> 1) & 3);
    src_off[c] = (int64_t)r * KEXT + cc * 8;
    lds_off[c] = g * 16;
  }

  // fragment read byte offsets (K-invariant), swizzled
  int aoff[4], boff[4];
#pragma unroll
  for (int i = 0; i < 4; i++) {
    int ra = wm * 64 + i * 16 + l15;
    aoff[i] = ra * 64 + ((lk ^ ((ra >> 1) & 3)) << 4);
    int rb = wn * 64 + i * 16 + l15;
    boff[i] = rb * 64 + ((lk ^ ((rb >> 1) & 3)) << 4);
  }

  f32x4a acc[4][4];
#pragma unroll
  for (int i = 0; i < 4; i++)
#pragma unroll
    for (int j = 0; j < 4; j++) acc[i][j] = (f32x4a){0.f, 0.f, 0.f, 0.f};

  char* ldsAb = (char*)ldsA;
  char* ldsBb = (char*)ldsB;

  for (int k0 = 0; k0 < KEXT; k0 += 32) {
    gload16(ldsAb + lds_off[0], Ap + k0 + src_off[0]);
    gload16(ldsAb + lds_off[1], Ap + k0 + src_off[1]);
    gload16(ldsBb + lds_off[0], Bp + k0 + src_off[0]);
    gload16(ldsBb + lds_off[1], Bp + k0 + src_off[1]);
    __syncthreads();   // compiler drains vmcnt before s_barrier
    s16x8 af[4], bf[4];
#pragma unroll
    for (int i = 0; i < 4; i++) af[i] = *(const s16x8*)(ldsAb + aoff[i]);
#pragma unroll
    for (int i = 0; i < 4; i++) bf[i] = *(const s16x8*)(ldsBb + boff[i]);
#pragma unroll
    for (int i = 0; i < 4; i++)
#pragma unroll
      for (int j = 0; j < 4; j++)
        acc[i][j] = __builtin_amdgcn_mfma_f32_16x16x32_bf16(af[i], bf[j],
                                                            acc[i][j], 0, 0, 0);
    __syncthreads();
  }

  // epilogue: out = acc * (qscale[n]*meta) + bias[n]
  const float mv = meta[0];
  const int64_t mrow0 = (int64_t)mtile * 128 + wm * 64;
  const int ncol0 = ntile * 128 + wn * 64;
#pragma unroll
  for (int j = 0; j < 4; j++) {
    int n = ncol0 + j * 16 + l15;
    float sr = (float)qscale[n] * mv;
    float bv = bias[n];
#pragma unroll
    for (int i = 0; i < 4; i++) {
      float* op = out + (mrow0 + i * 16 + lk * 4) * (int64_t)D_OUT + n;
#pragma unroll
      for (int reg = 0; reg < 4; reg++)
        op[(int64_t)reg * D_OUT] = acc[i][j][reg] * sr + bv;
    }
  }
}

extern "C" void kernel_launch(void* const* d_in, const int* in_sizes, int n_in,
                              void* d_out, int out_size, void* d_ws, size_t ws_size,
                              hipStream_t stream) {
  const float* x    = (const float*)d_in[0];
  const int*   qw   = (const int*)d_in[1];
  const int*   qs   = (const int*)d_in[2];
  const float* meta = (const float*)d_in[3];
  const float* bias = (const float*)d_in[4];
  const float* lA   = (const float*)d_in[5];
  const float* lB   = (const float*)d_in[6];
  float* out = (float*)d_out;

  uint16_t* xext = (uint16_t*)d_ws;                       // 8192*4128*2 B
  uint16_t* wext = xext + (size_t)MROWS * KEXT;           // 4096*4128*2 B
  const size_t need = ((size_t)MROWS + D_OUT) * KEXT * 2; // 101,449,728 B
  if (ws_size < need) return;  // clean fail (absmax stays at poison) rather than OOB

  k_conv_x<<<2048, 256, 0, stream>>>(x, xext);
  k_xa<<<MROWS / 64, 256, 0, stream>>>(xext, xext, lA);
  k_conv_w<<<D_OUT, 256, 0, stream>>>(qw, qs, meta, lB, wext);
  k_gemm<<<2048, 256, 0, stream>>>(xext, wext, qs, meta, bias, out);
}

// Round 2
// 349.028 us; speedup vs baseline: 1.5244x; 1.5244x over previous
//
#include <hip/hip_runtime.h>
#include <hip/hip_bf16.h>
#include <stdint.h>

typedef short   s16x8  __attribute__((ext_vector_type(8)));
typedef float   f32x4a __attribute__((ext_vector_type(4)));
typedef unsigned short u16x4 __attribute__((ext_vector_type(4)));
typedef int     i32x4  __attribute__((ext_vector_type(4)));

#define D_IN   4096
#define D_OUT  4096
#define RANK   16
#define KEXT   4128   // 4096 + 16 (lora) + 16 (zero pad); 129 * 32
#define MROWS  8192   // 4 * 2048
#define NT     (KEXT / 32)   // 129 K-tiles
#define LDS_TILE (256 * 32)  // elems per matrix per buffer (16 KB)

__device__ __forceinline__ uint16_t f32_to_bf16(float f) {
  union { float f; uint32_t u; } v; v.f = f;
  uint32_t u = v.u;
  return (uint16_t)((u + 0x7FFFu + ((u >> 16) & 1u)) >> 16);  // RNE
}

__device__ __forceinline__ void gload16(void* lds, const void* g) {
  __builtin_amdgcn_global_load_lds(
      (const __attribute__((address_space(1))) uint32_t*)g,
      (__attribute__((address_space(3))) uint32_t*)lds, 16, 0, 0);
}

// ---- 1) x fp32 -> bf16 into x_ext (row stride KEXT) --------------------
extern "C" __global__ void k_conv_x(const float* __restrict__ x,
                                    uint16_t* __restrict__ xext) {
  int64_t idx = (int64_t)blockIdx.x * blockDim.x + threadIdx.x;  // float4 index
  const int64_t total  = (int64_t)MROWS * (D_IN / 4);
  const int64_t stride = (int64_t)gridDim.x * blockDim.x;
  for (; idx < total; idx += stride) {
    int64_t m = idx >> 10;              // D_IN/4 = 1024
    int k4 = (int)(idx & 1023);
    f32x4a v = *(const f32x4a*)(x + m * D_IN + (int64_t)k4 * 4);
    u16x4 o;
#pragma unroll
    for (int j = 0; j < 4; j++) o[j] = f32_to_bf16(v[j]);
    *(u16x4*)(xext + m * KEXT + k4 * 4) = o;
  }
}

// ---- 2) xA = x_bf16 @ loraA^T via MFMA, into x_ext cols [4096,4128) ----
extern "C" __global__ __launch_bounds__(256) void k_xa(
    const uint16_t* __restrict__ xext_ro, uint16_t* __restrict__ xext_rw,
    const float* __restrict__ loraA) {
  const int tid = threadIdx.x, w = tid >> 6, l = tid & 63;
  const int l15 = l & 15, lk = l >> 4;
  const int64_t row0 = (int64_t)blockIdx.x * 64 + w * 16;
  f32x4a acc = {0.f, 0.f, 0.f, 0.f};
  const uint16_t* xrow = xext_ro + (row0 + l15) * KEXT + lk * 8;
  const float*    arow = loraA + (int64_t)l15 * D_IN + lk * 8;
  for (int k0 = 0; k0 < D_IN; k0 += 32) {
    s16x8 af = *(const s16x8*)(xrow + k0);
    s16x8 bf;
#pragma unroll
    for (int j = 0; j < 8; j++) bf[j] = (short)f32_to_bf16(arow[k0 + j]);
    acc = __builtin_amdgcn_mfma_f32_16x16x32_bf16(af, bf, acc, 0, 0, 0);
  }
#pragma unroll
  for (int reg = 0; reg < 4; reg++) {
    int64_t m = row0 + lk * 4 + reg;
    xext_rw[m * KEXT + D_IN + l15]        = f32_to_bf16(acc[reg]);
    xext_rw[m * KEXT + D_IN + RANK + l15] = (uint16_t)0;  // zero pad
  }
}

// ---- 3) qweight int -> bf16 + LoRA-B tail into w_ext -------------------
extern "C" __global__ void k_conv_w(const int* __restrict__ qw,
                                    const int* __restrict__ qscale,
                                    const float* __restrict__ meta,
                                    const float* __restrict__ loraB,
                                    uint16_t* __restrict__ wext) {
  const int n = blockIdx.x, t = threadIdx.x;
  const int* row  = qw   + (int64_t)n * D_IN;
  uint16_t*  orow = wext + (int64_t)n * KEXT;
  const int base = t * 16;
#pragma unroll
  for (int j = 0; j < 4; j++) {
    i32x4 v = *(const i32x4*)(row + base + j * 4);
    u16x4 o;
#pragma unroll
    for (int e = 0; e < 4; e++) o[e] = f32_to_bf16((float)v[e]);  // exact
    *(u16x4*)(orow + base + j * 4) = o;
  }
  if (t < RANK) {
    float sr = (float)qscale[n] * meta[0];
    orow[D_IN + t] = f32_to_bf16(2.0f * loraB[n * RANK + t] / sr);
  } else if (t < 2 * RANK) {
    orow[D_IN + t] = (uint16_t)0;  // zero pad
  }
}

// ---- 4) main GEMM: C = Xext @ Wext^T, 256x256 tile, BK=32 --------------
// 8 waves (2m x 4n), per-wave 128x64 out. 3 rotating LDS buffers; tile t+2
// staged (global_load_lds w=16) during tile t -> counted vmcnt(4) at tile
// boundary, never 0 in steady state. LDS layout [rowblk][kchunk][16][16B]:
// linear gload dest AND contiguous b128 fragment reads (no bank conflicts).
extern "C" __global__ __launch_bounds__(512, 2) void k_gemm(
    const uint16_t* __restrict__ A, const uint16_t* __restrict__ B,
    const int* __restrict__ qscale, const float* __restrict__ meta,
    const float* __restrict__ bias, float* __restrict__ out) {
  extern __shared__ uint16_t lds[];            // 96 KB dynamic
  uint16_t* ldsA = lds;                        // [3][LDS_TILE]
  uint16_t* ldsB = lds + 3 * LDS_TILE;

  const int tid = threadIdx.x;
  const int bid = blockIdx.x;                  // 512 blocks, 512%8==0
  const int xcd = bid & 7, loc = bid >> 3;     // bijective XCD swizzle
  const int mtile = xcd * 4 + (loc & 3);       // 0..31
  const int ntile = loc >> 2;                  // 0..15

  const int w = tid >> 6, l = tid & 63;
  const int wm = w >> 2, wn = w & 3;
  const int l15 = l & 15, lk = l >> 4;

  const uint16_t* Ag = A + (int64_t)mtile * 256 * KEXT;
  const uint16_t* Bg = B + (int64_t)ntile * 256 * KEXT;

  // staging map: granule g -> (row, kchunk): row = ((g>>6)<<4)|(g&15),
  // kchunk = (g>>4)&3; dest byte = g*16 (linear in lane).
  const int row0 = ((tid >> 6) << 4) | (tid & 15);
  const int lk0  = (tid >> 4) & 3;
  const int64_t soff0 = (int64_t)row0 * KEXT + lk0 * 8;
  const int64_t soff1 = soff0 + (int64_t)128 * KEXT;
  const int dst0 = tid * 16, dst1 = dst0 + 8192;

#define STAGE_A(bi, kt) { char* p_ = (char*)(ldsA + (bi) * LDS_TILE); \
    gload16(p_ + dst0, Ag + (int64_t)(kt) * 32 + soff0);              \
    gload16(p_ + dst1, Ag + (int64_t)(kt) * 32 + soff1); }
#define STAGE_B(bi, kt) { char* p_ = (char*)(ldsB + (bi) * LDS_TILE); \
    gload16(p_ + dst0, Bg + (int64_t)(kt) * 32 + soff0);              \
    gload16(p_ + dst1, Bg + (int64_t)(kt) * 32 + soff1); }

  // fragment byte offset within a tile: element (row, kchunk lk) lives at
  // (row>>4)*1024 + lk*256 + (row&15)*16
  const int fro = lk * 256 + l15 * 16;

  f32x4a acc[8][4];
#pragma unroll
  for (int i = 0; i < 8; i++)
#pragma unroll
    for (int j = 0; j < 4; j++) acc[i][j] = (f32x4a){0.f, 0.f, 0.f, 0.f};

  // prologue: stage tiles 0 and 1; wait tile 0 (tile 1 stays in flight)
  STAGE_A(0, 0); STAGE_B(0, 0);
  STAGE_A(1, 1); STAGE_B(1, 1);
  asm volatile("s_waitcnt vmcnt(4)" ::: "memory");
  asm volatile("s_barrier" ::: "memory");

  int cur = 0;
  for (int kt = 0; kt < NT; ++kt) {
    const int b2 = (cur >= 1) ? cur - 1 : 2;   // (kt+2)%3
    const bool st = (kt + 2 < NT);
    const char* cA = (const char*)(ldsA + cur * LDS_TILE);
    const char* cB = (const char*)(ldsB + cur * LDS_TILE);

    // ---- phase 0: quadrant mi 0..3 ----
    if (st) STAGE_A(b2, kt + 2);
    s16x8 bf[4], af[4];
#pragma unroll
    for (int ni = 0; ni < 4; ++ni)
      bf[ni] = *(const s16x8*)(cB + (wn * 4 + ni) * 1024 + fro);
#pragma unroll
    for (int mi = 0; mi < 4; ++mi)
      af[mi] = *(const s16x8*)(cA + (wm * 8 + mi) * 1024 + fro);
    asm volatile("s_barrier" ::: "memory");
    __builtin_amdgcn_s_setprio(1);
#pragma unroll
    for (int mi = 0; mi < 4; ++mi)
#pragma unroll
      for (int ni = 0; ni < 4; ++ni)
        acc[mi][ni] = __builtin_amdgcn_mfma_f32_16x16x32_bf16(
            af[mi], bf[ni], acc[mi][ni], 0, 0, 0);
    __builtin_amdgcn_s_setprio(0);
    asm volatile("s_barrier" ::: "memory");

    // ---- phase 1: quadrant mi 4..7 ----
    if (st) STAGE_B(b2, kt + 2);
#pragma unroll
    for (int mi = 0; mi < 4; ++mi)
      af[mi] = *(const s16x8*)(cA + (wm * 8 + 4 + mi) * 1024 + fro);
    asm volatile("s_barrier" ::: "memory");
    __builtin_amdgcn_s_setprio(1);
#pragma unroll
    for (int mi = 0; mi < 4; ++mi)
#pragma unroll
      for (int ni = 0; ni < 4; ++ni)
        acc[4 + mi][ni] = __builtin_amdgcn_mfma_f32_16x16x32_bf16(
            af[mi], bf[ni], acc[4 + mi][ni], 0, 0, 0);
    __builtin_amdgcn_s_setprio(0);
    // end-of-tile wait: keep tile t+2's 4 loads in flight (counted, not 0)
    if (st)                asm volatile("s_waitcnt vmcnt(4)" ::: "memory");
    else if (kt + 1 < NT)  asm volatile("s_waitcnt vmcnt(0)" ::: "memory");
    asm volatile("s_barrier" ::: "memory");

    cur = (cur == 2) ? 0 : cur + 1;
  }

  // epilogue: out = acc * (qscale[n]*meta) + bias[n]
  const float mv = meta[0];
  const int64_t mrow0 = (int64_t)mtile * 256 + wm * 128;
  const int ncol0 = ntile * 256 + wn * 64;
#pragma unroll
  for (int ni = 0; ni < 4; ++ni) {
    int n = ncol0 + ni * 16 + l15;
    float sr = (float)qscale[n] * mv;
    float bv = bias[n];
#pragma unroll
    for (int mi = 0; mi < 8; ++mi) {
      float* op = out + (mrow0 + mi * 16 + lk * 4) * (int64_t)D_OUT + n;
#pragma unroll
      for (int reg = 0; reg < 4; reg++)
        op[(int64_t)reg * D_OUT] = acc[mi][ni][reg] * sr + bv;
    }
  }
#undef STAGE_A
#undef STAGE_B
}

extern "C" void kernel_launch(void* const* d_in, const int* in_sizes, int n_in,
                              void* d_out, int out_size, void* d_ws, size_t ws_size,
                              hipStream_t stream) {
  const float* x    = (const float*)d_in[0];
  const int*   qw   = (const int*)d_in[1];
  const int*   qs   = (const int*)d_in[2];
  const float* meta = (const float*)d_in[3];
  const float* bias = (const float*)d_in[4];
  const float* lA   = (const float*)d_in[5];
  const float* lB   = (const float*)d_in[6];
  float* out = (float*)d_out;

  uint16_t* xext = (uint16_t*)d_ws;                       // 8192*4128*2 B
  uint16_t* wext = xext + (size_t)MROWS * KEXT;           // 4096*4128*2 B
  const size_t need = ((size_t)MROWS + D_OUT) * KEXT * 2; // 101,449,728 B
  if (ws_size < need) return;

  const int lds_bytes = 6 * LDS_TILE * 2;                 // 96 KB
  (void)hipFuncSetAttribute((const void*)k_gemm,
                            hipFuncAttributeMaxDynamicSharedMemorySize,
                            lds_bytes);

  k_conv_x<<<2048, 256, 0, stream>>>(x, xext);
  k_xa<<<MROWS / 64, 256, 0, stream>>>(xext, xext, lA);
  k_conv_w<<<D_OUT, 256, 0, stream>>>(qw, qs, meta, lB, wext);
  k_gemm<<<512, 512, lds_bytes, stream>>>(xext, wext, qs, meta, bias, out);
}